// Round 23
// baseline (23.843 us; speedup 1.0000x reference)
//
#include <hip/hip_runtime.h>
#include <hip/hip_bf16.h>

#define N_X    65536
#define N_IND  1024
#define N_DESC 64
#define TILES  (N_IND / 16)       // 64 MFMA row-tiles (full z-panel)
#define L2E    1.4426950408889634f
#define L2E2   2.8853900817779268f
#define SKIP_THR (-60.0f)         // 2^-60 * 1024 * |alpha| ~ 4e-15 << tol

typedef __attribute__((ext_vector_type(8))) short  short8;
typedef __attribute__((ext_vector_type(4))) float  f32x4;
typedef __attribute__((ext_vector_type(2))) float  f32x2;

static __device__ __forceinline__ ushort f2bf(float f) {
    union { float f; unsigned u; } a; a.f = f;
    unsigned r = a.u + 0x7FFF + ((a.u >> 16) & 1);   // RNE to bf16
    return (ushort)(r >> 16);
}
static __device__ __forceinline__ float bf2f(ushort h) {
    union { unsigned u; float f; } a; a.u = (unsigned)h << 16;
    return a.f;
}

// async global->LDS DMA (gfx950). LDS dest = wave-uniform base + lane*size.
static __device__ __forceinline__ void gl_lds16(const void* g, void* l) {
    __builtin_amdgcn_global_load_lds(
        (const __attribute__((address_space(1))) unsigned int*)g,
        (__attribute__((address_space(3))) unsigned int*)l, 16, 0, 0);
}
static __device__ __forceinline__ void gl_lds4(const void* g, void* l) {
    __builtin_amdgcn_global_load_lds(
        (const __attribute__((address_space(1))) unsigned int*)g,
        (__attribute__((address_space(3))) unsigned int*)l, 4, 0, 0);
}

// ---------------------------------------------------------------------------
// prep: convert z ONCE chip-wide into the exact XOR-swizzled bf16 byte image
// the fused kernel's LDS panel uses (byte = row*128 + ((gr*16)^((row&7)<<4)))
// plus z2w[row] = log2e*||zw_row||^2 (bf16-rounded, matching fused's math).
// 4 blocks x 256 threads; thread = one z row. 132 KB total ws writes.
// ---------------------------------------------------------------------------
__global__ __launch_bounds__(256) void igpr_prep(
        const float* __restrict__ z, const float* __restrict__ ls,
        uint4* __restrict__ ztw, float* __restrict__ z2w) {
    __shared__ float wls[N_DESC];
    const int tid = threadIdx.x;
    if (tid < N_DESC) wls[tid] = __expf(-0.5f * ls[tid]);
    __syncthreads();

    const int r = blockIdx.x * 256 + tid;
    const float* zr = z + (size_t)r * N_DESC;
    char* zb = reinterpret_cast<char*>(ztw);
    float sq = 0.f;
#pragma unroll
    for (int gr = 0; gr < 8; ++gr) {
        float4 v0 = *reinterpret_cast<const float4*>(zr + gr * 8);
        float4 v1 = *reinterpret_cast<const float4*>(zr + gr * 8 + 4);
        float vv[8] = {v0.x, v0.y, v0.z, v0.w, v1.x, v1.y, v1.z, v1.w};
        ushort hb[8];
#pragma unroll
        for (int e = 0; e < 8; ++e) {
            ushort h = f2bf(vv[e] * wls[gr * 8 + e]);
            hb[e] = h;
            float vr = bf2f(h);
            sq = fmaf(vr, vr, sq);
        }
        uint4 u = make_uint4(
            (unsigned)hb[0] | ((unsigned)hb[1] << 16),
            (unsigned)hb[2] | ((unsigned)hb[3] << 16),
            (unsigned)hb[4] | ((unsigned)hb[5] << 16),
            (unsigned)hb[6] | ((unsigned)hb[7] << 16));
        *reinterpret_cast<uint4*>(zb + r * 128 + ((gr * 16) ^ ((r & 7) << 4))) = u;
    }
    z2w[r] = sq * L2E;
}

// ---------------------------------------------------------------------------
// fused (R19 loop, DMA staging): staging = 8x16B-wide global_load_lds per
// wave (pre-swizzled image -> linear copy, zero VALU / zero VGPR) + 1 each
// for z2/alpha. Issue order: x loads (oldest, so x-convert's vmcnt wait
// doesn't block on the DMAs) -> DMAs -> convert; __syncthreads drains all.
// Skip bound simplified to thr = SKIP_THR + xs2 (sound: z2 >= 0; margin
// ~860 vs sigma ~230 -> all tiles still skip; exact kept path otherwise).
// Loop/coverage identical to R19: 16 waves x 16 cols, 64 tiles, 2 swizzled
// conflict-free ds_read_b128 + 2 chained MFMA + 4-op test per tile.
// C/D: col = lane&15 (x-col), row = 4*(lane>>4)+reg (z-row).
// ---------------------------------------------------------------------------
__global__ __launch_bounds__(1024) void igpr_fused(
        const float* __restrict__ x, const uint4* __restrict__ ztw,
        const float* __restrict__ z2w, const float* __restrict__ alpha,
        const float* __restrict__ ls, float* __restrict__ out) {
    struct SM {
        uint4 zt[N_IND * 8];   // 1024 rows * 128 B = 128 KB (swizzled image)
        float z2[N_IND];       // log2e * ||zw_i||^2
        float al[N_IND];       // alpha
    };
    __shared__ SM sm;          // 136 KB of the CU's 160 KB

    const int tid  = threadIdx.x;
    const int lane = tid & 63;
    const int wave = tid >> 6;
    const int p = lane & 15;          // x-col within strip / D col
    const int g = lane >> 4;          // k-group; D rows 4g..4g+3 (z-rows)
    const int j = blockIdx.x * 256 + wave * 16 + p;   // this lane's x column

    // ---- x loads first (oldest in vmcnt queue) ----
    const float* xr = x + (size_t)j * N_DESC;
    float4 xv0 = *reinterpret_cast<const float4*>(xr + g * 8);
    float4 xv1 = *reinterpret_cast<const float4*>(xr + g * 8 + 4);
    float4 xv2 = *reinterpret_cast<const float4*>(xr + 32 + g * 8);
    float4 xv3 = *reinterpret_cast<const float4*>(xr + 32 + g * 8 + 4);

    // ---- async DMA staging: panel 8 KB/wave + z2/al 256 B/wave ----
    {
        const char* gp = reinterpret_cast<const char*>(ztw)
                       + wave * 8192 + lane * 16;
        char* lp = reinterpret_cast<char*>(sm.zt) + wave * 8192;  // uniform
#pragma unroll
        for (int i = 0; i < 8; ++i)
            gl_lds16(gp + i * 1024, lp + i * 1024);
        gl_lds4(z2w   + wave * 64 + lane, &sm.z2[wave * 64]);
        gl_lds4(alpha + wave * 64 + lane, &sm.al[wave * 64]);
    }

    // ---- convert x + xs2 (waits only on the x loads) ----
    short8 b0, b1;
    float xs2;
    {
        float wx[16];
#pragma unroll
        for (int h = 0; h < 2; ++h)
#pragma unroll
            for (int e = 0; e < 8; ++e)
                wx[h * 8 + e] = __expf(-0.5f * ls[h * 32 + g * 8 + e]);
        float vv[16] = {xv0.x, xv0.y, xv0.z, xv0.w, xv1.x, xv1.y, xv1.z, xv1.w,
                        xv2.x, xv2.y, xv2.z, xv2.w, xv3.x, xv3.y, xv3.z, xv3.w};
        float sq = 0.f;
        short8 bb[2];
#pragma unroll
        for (int h = 0; h < 2; ++h)
#pragma unroll
            for (int e = 0; e < 8; ++e) {
                ushort hh = f2bf(vv[h * 8 + e] * wx[h * 8 + e]);
                bb[h][e] = (short)hh;
                float xv = bf2f(hh);
                sq = fmaf(xv, xv, sq);
            }
        b0 = bb[0]; b1 = bb[1];
        sq += __shfl_xor(sq, 16);
        sq += __shfl_xor(sq, 32);
        xs2 = sq * L2E;
    }

    __syncthreads();   // drains vmcnt(0): panel + z2 + al resident

    const float thr = SKIP_THR + xs2;   // z2 >= 0: sound skip bound

    const char* zb = reinterpret_cast<const char*>(sm.zt);
    const int rb0 = p * 128 + ((16 * g)      ^ ((p & 7) << 4));
    const int rb1 = p * 128 + ((64 + 16 * g) ^ ((p & 7) << 4));

    f32x2 accJ = {0.f, 0.f};
    const f32x2 xs2p = {xs2, xs2};

#pragma unroll 4
    for (int it = 0; it < TILES; ++it) {
        short8 a0 = *reinterpret_cast<const short8*>(zb + it * 2048 + rb0);
        short8 a1 = *reinterpret_cast<const short8*>(zb + it * 2048 + rb1);

        f32x4 t = {0.f, 0.f, 0.f, 0.f};
        t = __builtin_amdgcn_mfma_f32_16x16x32_bf16(a0, b0, t, 0, 0, 0);
        t = __builtin_amdgcn_mfma_f32_16x16x32_bf16(a1, b1, t, 0, 0, 0);

        float maxdot = fmaxf(fmaxf(t[0], t[1]), fmaxf(t[2], t[3]));

        if (!__all(maxdot * L2E2 < thr)) {
            // rare path: a real contribution may exist in this tile
            float4 z2 = *reinterpret_cast<const float4*>(&sm.z2[it * 16 + g * 4]);
            float4 a4 = *reinterpret_cast<const float4*>(&sm.al[it * 16 + g * 4]);
            f32x2 z2p0 = {z2.x, z2.y}, z2p1 = {z2.z, z2.w};
            f32x2 d0 = {t[0], t[1]}, d1 = {t[2], t[3]};
            f32x2 arg0 = d0 * L2E2 - (z2p0 + xs2p);
            f32x2 arg1 = d1 * L2E2 - (z2p1 + xs2p);
            f32x2 pv0 = {__builtin_amdgcn_exp2f(arg0.x),
                         __builtin_amdgcn_exp2f(arg0.y)};
            f32x2 pv1 = {__builtin_amdgcn_exp2f(arg1.x),
                         __builtin_amdgcn_exp2f(arg1.y)};
            f32x2 a4p0 = {a4.x, a4.y}, a4p1 = {a4.z, a4.w};
            accJ = accJ + a4p0 * pv0;              // pk_fma
            accJ = accJ + a4p1 * pv1;              // pk_fma
        }
    }

    float r = accJ.x + accJ.y;
    r += __shfl_xor(r, 16);
    r += __shfl_xor(r, 32);
    if (g == 0) out[j] = r;
}

extern "C" void kernel_launch(void* const* d_in, const int* in_sizes, int n_in,
                              void* d_out, int out_size, void* d_ws, size_t ws_size,
                              hipStream_t stream) {
    const float* x     = (const float*)d_in[0];   // (65536, 64)
    const float* z     = (const float*)d_in[1];   // (1024, 64)
    const float* alpha = (const float*)d_in[2];   // (1024,)
    const float* ls    = (const float*)d_in[3];   // (64,)
    float* out = (float*)d_out;                   // (65536, 1)

    // ws layout: ztw uint4[8192] (128 KB swizzled panel) | z2w f32[1024]
    uint4* ztw = (uint4*)d_ws;
    float* z2w = (float*)(ztw + (size_t)N_IND * 8);

    igpr_prep<<<dim3(4), dim3(256), 0, stream>>>(z, ls, ztw, z2w);
    igpr_fused<<<dim3(N_X / 256), dim3(1024), 0, stream>>>(
        x, ztw, z2w, alpha, ls, out);
}

// Round 24
// 21.637 us; speedup vs baseline: 1.1019x; 1.1019x over previous
//
#include <hip/hip_runtime.h>
#include <hip/hip_bf16.h>

#define N_X    65536
#define N_IND  1024
#define N_DESC 64
#define TILES  (N_IND / 16)       // 64 MFMA row-tiles (full z-panel)
#define L2E    1.4426950408889634f
#define L2E2   2.8853900817779268f
#define SKIP_THR (-60.0f)         // 2^-60 * 1024 * |alpha| ~ 4e-15 << tol

typedef __attribute__((ext_vector_type(8))) short  short8;
typedef __attribute__((ext_vector_type(4))) float  f32x4;
typedef __attribute__((ext_vector_type(2))) float  f32x2;

static __device__ __forceinline__ ushort f2bf(float f) {
    union { float f; unsigned u; } a; a.f = f;
    unsigned r = a.u + 0x7FFF + ((a.u >> 16) & 1);   // RNE to bf16
    return (ushort)(r >> 16);
}
static __device__ __forceinline__ float bf2f(ushort h) {
    union { unsigned u; float f; } a; a.u = (unsigned)h << 16;
    return a.f;
}

// ---------------------------------------------------------------------------
// Round 24 = R22 with SPLIT-PANEL STAGING OVERLAP. R20/R23 budget analysis:
// loop ~6.5 us, staging+prologue ~11 us, dominated by the per-block z f32
// re-read (67 MB chip-wide from L3) on the pre-barrier critical path.
// Now only rows 0-511 (granules 0-3) are staged before barrier-1; granules
// 4-7 are interleaved into the first 32 tiles as 4 chunks of
//   { issue next granule loads -> 8 tiles -> convert+write prev granule }
// so half the z traffic + conversion VALU hides under the (LDS-bound)
// loop-half-1. barrier-2 publishes rows 512-1023 before tiles 32-63.
// Disjointness: loop-half-1 reads LDS bytes 0-64K / z2[0..511] only; chunk
// writes touch bytes 64-128K / z2[512..1023] only. Skip bound: thr =
// SKIP_THR + xs2 (z2>=0, sound; validated R23 - no zmin, no z2 read in the
// common path). Kept path = exact R12 math (never fires for this data).
// Everything else identical to R22 (best verified: 20.21 us): early x
// loads, 2-deep pipelined granule staging, XOR-swizzled panel (byte colb ^=
// (row&7)<<4 both sides, rule #21), 16 waves x 16 cols (full coverage),
// 2 conflict-free ds_read_b128 + 2 chained MFMA + 4-op test per tile.
// C/D: col = lane&15 (x-col), row = 4*(lane>>4)+reg (z-row).
// ---------------------------------------------------------------------------
__global__ __launch_bounds__(1024) void igpr_fused(
        const float* __restrict__ x, const float* __restrict__ z,
        const float* __restrict__ alpha, const float* __restrict__ ls,
        float* __restrict__ out) {
    struct SM {
        uint4 zt[N_IND * 8];   // 1024 rows * 128 B = 128 KB (swizzled)
        float z2[N_IND];       // log2e * ||zw_i||^2
        float al[N_IND];       // alpha
    };
    __shared__ SM sm;          // 136 KB of the CU's 160 KB

    const int tid  = threadIdx.x;
    const int lane = tid & 63;
    const int wave = tid >> 6;
    const int p = lane & 15;          // x-col within strip / D col
    const int g = lane >> 4;          // k-group; D rows 4g..4g+3 (z-rows)
    const int j = blockIdx.x * 256 + wave * 16 + p;   // this lane's x column

    // ---- issue x loads immediately; consumed after half-1 staging ----
    const float* xr = x + (size_t)j * N_DESC;
    float4 xv0 = *reinterpret_cast<const float4*>(xr + g * 8);
    float4 xv1 = *reinterpret_cast<const float4*>(xr + g * 8 + 4);
    float4 xv2 = *reinterpret_cast<const float4*>(xr + 32 + g * 8);
    float4 xv3 = *reinterpret_cast<const float4*>(xr + 32 + g * 8 + 4);
    float  alv = alpha[tid];          // N_IND == blockDim.x

    // ---- per-thread staging weights: cols gr*8 .. gr*8+7 ----
    const int gr = tid & 7;           // granule column-group (fixed per thread)
    const int row_base = tid >> 3;    // row = rb*128 + row_base
    float wz[8];
#pragma unroll
    for (int e = 0; e < 8; ++e) wz[e] = __expf(-0.5f * ls[gr * 8 + e]);

    char* zbw = reinterpret_cast<char*>(sm.zt);

#define ZLD(rb, A, B)                                                          \
    {                                                                          \
        const float* zp_ = z + (size_t)((rb) * 128 + row_base) * 64 + gr * 8;  \
        A = *reinterpret_cast<const float4*>(zp_);                             \
        B = *reinterpret_cast<const float4*>(zp_ + 4);                         \
    }
#define ZCVT(rb, A, B)                                                         \
    {                                                                          \
        float vv_[8] = {A.x, A.y, A.z, A.w, B.x, B.y, B.z, B.w};               \
        ushort hb_[8]; float sq_ = 0.f;                                        \
        _Pragma("unroll")                                                      \
        for (int e = 0; e < 8; ++e) {                                          \
            ushort h_ = f2bf(vv_[e] * wz[e]);                                  \
            hb_[e] = h_;                                                       \
            float vr_ = bf2f(h_);                                              \
            sq_ = fmaf(vr_, vr_, sq_);                                         \
        }                                                                      \
        uint4 u_ = make_uint4(                                                 \
            (unsigned)hb_[0] | ((unsigned)hb_[1] << 16),                       \
            (unsigned)hb_[2] | ((unsigned)hb_[3] << 16),                       \
            (unsigned)hb_[4] | ((unsigned)hb_[5] << 16),                       \
            (unsigned)hb_[6] | ((unsigned)hb_[7] << 16));                      \
        int row_ = (rb) * 128 + row_base;                                      \
        int sw_  = row_ * 128 + ((gr * 16) ^ ((row_ & 7) << 4));               \
        *reinterpret_cast<uint4*>(zbw + sw_) = u_;                             \
        sq_ += __shfl_xor(sq_, 1);                                             \
        sq_ += __shfl_xor(sq_, 2);                                             \
        sq_ += __shfl_xor(sq_, 4);                                             \
        if (gr == 0) sm.z2[row_] = sq_ * L2E;                                  \
    }

    // ---- half-1 staging (rows 0-511): granules 0-3, 2-deep pipelined ----
    float4 cA, cB, nA, nB;
    ZLD(0, cA, cB)
    ZLD(1, nA, nB)
    ZCVT(0, cA, cB)  ZLD(2, cA, cB)
    ZCVT(1, nA, nB)  ZLD(3, nA, nB)
    ZCVT(2, cA, cB)
    ZCVT(3, nA, nB)

    sm.al[tid] = alv;

    // ---- convert x (loads long in flight) + xs2 ----
    short8 b0, b1;
    float xs2;
    {
        float wx[16];
#pragma unroll
        for (int h = 0; h < 2; ++h)
#pragma unroll
            for (int e = 0; e < 8; ++e)
                wx[h * 8 + e] = __expf(-0.5f * ls[h * 32 + g * 8 + e]);
        float vv[16] = {xv0.x, xv0.y, xv0.z, xv0.w, xv1.x, xv1.y, xv1.z, xv1.w,
                        xv2.x, xv2.y, xv2.z, xv2.w, xv3.x, xv3.y, xv3.z, xv3.w};
        float sq = 0.f;
        short8 bb[2];
#pragma unroll
        for (int h = 0; h < 2; ++h)
#pragma unroll
            for (int e = 0; e < 8; ++e) {
                ushort hh = f2bf(vv[h * 8 + e] * wx[h * 8 + e]);
                bb[h][e] = (short)hh;
                float xv = bf2f(hh);
                sq = fmaf(xv, xv, sq);
            }
        b0 = bb[0]; b1 = bb[1];
        sq += __shfl_xor(sq, 16);
        sq += __shfl_xor(sq, 32);
        xs2 = sq * L2E;
    }

    __syncthreads();   // half-1 panel (bytes 0-64K) + z2[0..511] + al ready

    const float thr = SKIP_THR + xs2;   // z2 >= 0: sound skip bound (R23)

    const char* zb = reinterpret_cast<const char*>(sm.zt);
    const int rb0 = p * 128 + ((16 * g)      ^ ((p & 7) << 4));
    const int rb1 = p * 128 + ((64 + 16 * g) ^ ((p & 7) << 4));

    f32x2 accJ = {0.f, 0.f};
    const f32x2 xs2p = {xs2, xs2};

    auto run_tiles = [&](int itb, int ite) {
#pragma unroll 4
        for (int it = itb; it < ite; ++it) {
            short8 a0 = *reinterpret_cast<const short8*>(zb + it * 2048 + rb0);
            short8 a1 = *reinterpret_cast<const short8*>(zb + it * 2048 + rb1);

            f32x4 t = {0.f, 0.f, 0.f, 0.f};
            t = __builtin_amdgcn_mfma_f32_16x16x32_bf16(a0, b0, t, 0, 0, 0);
            t = __builtin_amdgcn_mfma_f32_16x16x32_bf16(a1, b1, t, 0, 0, 0);

            float maxdot = fmaxf(fmaxf(t[0], t[1]), fmaxf(t[2], t[3]));

            if (!__all(maxdot * L2E2 < thr)) {
                // rare path: a real contribution may exist in this tile
                float4 z2 = *reinterpret_cast<const float4*>(&sm.z2[it * 16 + g * 4]);
                float4 a4 = *reinterpret_cast<const float4*>(&sm.al[it * 16 + g * 4]);
                f32x2 z2p0 = {z2.x, z2.y}, z2p1 = {z2.z, z2.w};
                f32x2 d0 = {t[0], t[1]}, d1 = {t[2], t[3]};
                f32x2 arg0 = d0 * L2E2 - (z2p0 + xs2p);
                f32x2 arg1 = d1 * L2E2 - (z2p1 + xs2p);
                f32x2 pv0 = {__builtin_amdgcn_exp2f(arg0.x),
                             __builtin_amdgcn_exp2f(arg0.y)};
                f32x2 pv1 = {__builtin_amdgcn_exp2f(arg1.x),
                             __builtin_amdgcn_exp2f(arg1.y)};
                f32x2 a4p0 = {a4.x, a4.y}, a4p1 = {a4.z, a4.w};
                accJ = accJ + a4p0 * pv0;          // pk_fma
                accJ = accJ + a4p1 * pv1;          // pk_fma
            }
        }
    };

    // ---- loop half-1 (tiles 0-31) with half-2 staging interleaved ----
    ZLD(4, cA, cB)            // issue granule-4 loads; land under tiles 0-7
    run_tiles(0, 8);
    ZLD(5, nA, nB)
    ZCVT(4, cA, cB)           // convert+write rows 512-639 (disjoint LDS)
    run_tiles(8, 16);
    ZLD(6, cA, cB)
    ZCVT(5, nA, nB)
    run_tiles(16, 24);
    ZLD(7, nA, nB)
    ZCVT(6, cA, cB)
    run_tiles(24, 32);
    ZCVT(7, nA, nB)
#undef ZLD
#undef ZCVT

    __syncthreads();   // half-2 panel (bytes 64-128K) + z2[512..1023] ready

    // ---- loop half-2 (tiles 32-63) ----
    run_tiles(32, TILES);

    float r = accJ.x + accJ.y;
    r += __shfl_xor(r, 16);
    r += __shfl_xor(r, 32);
    if (g == 0) out[j] = r;
}

extern "C" void kernel_launch(void* const* d_in, const int* in_sizes, int n_in,
                              void* d_out, int out_size, void* d_ws, size_t ws_size,
                              hipStream_t stream) {
    const float* x     = (const float*)d_in[0];   // (65536, 64)
    const float* z     = (const float*)d_in[1];   // (1024, 64)
    const float* alpha = (const float*)d_in[2];   // (1024,)
    const float* ls    = (const float*)d_in[3];   // (64,)
    float* out = (float*)d_out;                   // (65536, 1)

    igpr_fused<<<dim3(N_X / 256), dim3(1024), 0, stream>>>(x, z, alpha, ls, out);
}

// Round 25
// 20.618 us; speedup vs baseline: 1.1564x; 1.0494x over previous
//
#include <hip/hip_runtime.h>
#include <hip/hip_bf16.h>

#define N_X    65536
#define N_IND  1024
#define N_DESC 64
#define TILES  (N_IND / 16)       // 64 MFMA row-tiles (full z-panel)
#define L2E    1.4426950408889634f
#define L2E2   2.8853900817779268f
#define SKIP_THR (-60.0f)         // 2^-60 * 1024 * |alpha| ~ 4e-15 << tol

typedef __attribute__((ext_vector_type(8))) short  short8;
typedef __attribute__((ext_vector_type(4))) float  f32x4;
typedef __attribute__((ext_vector_type(2))) float  f32x2;

static __device__ __forceinline__ ushort f2bf(float f) {
    union { float f; unsigned u; } a; a.f = f;
    unsigned r = a.u + 0x7FFF + ((a.u >> 16) & 1);   // RNE to bf16
    return (ushort)(r >> 16);
}
static __device__ __forceinline__ float bf2f(ushort h) {
    union { unsigned u; float f; } a; a.u = (unsigned)h << 16;
    return a.f;
}

// ---------------------------------------------------------------------------
// Round 25 = R22 (champion structure: 20.21 us) with the z-staging pipeline
// deepened 2 -> 4. Budget: loop ~6.5 us, launch ~2.5, staging ~11 of which
// ~6 us is unhidden load latency (2-deep gave each load ~1 convert-window
// of ~100 cyc vs ~500-900 cyc L2/HBM latency). 4-deep: granules 0-3 issued
// before any convert; ZCVT(k) is followed by ZLD(k+4) into the freed regs,
// giving each load ~3 convert-windows. VGPR transient +16 (R13 measured 52
// for this structure -> ~68, far under the 128 cap for 16 waves). All else
// identical to R22: early x loads, XOR-swizzled panel (byte colb ^=
// (row&7)<<4 both sides, rule #21), 16 waves x 16 cols (coverage audited),
// 2 conflict-free ds_read_b128 + 2 chained MFMA + skip test per tile with
//   thr = SKIP_THR + xs2 + zmin   (sound; all tiles skip; exact R12 kept
// path if one ever fires). C/D: col = lane&15, row = 4*(lane>>4)+reg.
// ---------------------------------------------------------------------------
__global__ __launch_bounds__(1024) void igpr_fused(
        const float* __restrict__ x, const float* __restrict__ z,
        const float* __restrict__ alpha, const float* __restrict__ ls,
        float* __restrict__ out) {
    struct SM {
        uint4 zt[N_IND * 8];   // 1024 rows * 128 B = 128 KB (swizzled)
        float z2[N_IND];       // log2e * ||zw_i||^2
        float al[N_IND];       // alpha
    };
    __shared__ SM sm;          // 136 KB of the CU's 160 KB

    const int tid  = threadIdx.x;
    const int lane = tid & 63;
    const int wave = tid >> 6;
    const int p = lane & 15;          // x-col within strip / D col
    const int g = lane >> 4;          // k-group; D rows 4g..4g+3 (z-rows)
    const int j = blockIdx.x * 256 + wave * 16 + p;   // this lane's x column

    // ---- issue x loads immediately; consumed after z staging ----
    const float* xr = x + (size_t)j * N_DESC;
    float4 xv0 = *reinterpret_cast<const float4*>(xr + g * 8);
    float4 xv1 = *reinterpret_cast<const float4*>(xr + g * 8 + 4);
    float4 xv2 = *reinterpret_cast<const float4*>(xr + 32 + g * 8);
    float4 xv3 = *reinterpret_cast<const float4*>(xr + 32 + g * 8 + 4);
    float  alv = alpha[tid];          // N_IND == blockDim.x

    // ---- per-thread staging weights: cols gr*8 .. gr*8+7 ----
    const int gr = tid & 7;           // granule column-group (fixed per thread)
    const int row_base = tid >> 3;    // row = rb*128 + row_base
    float wz[8];
#pragma unroll
    for (int e = 0; e < 8; ++e) wz[e] = __expf(-0.5f * ls[gr * 8 + e]);

    // ---- z staging: 8 granules, 4-deep pipelined, swizzled dest ----
    char* zbw = reinterpret_cast<char*>(sm.zt);

#define ZLD(rb, A, B)                                                          \
    {                                                                          \
        const float* zp_ = z + (size_t)((rb) * 128 + row_base) * 64 + gr * 8;  \
        A = *reinterpret_cast<const float4*>(zp_);                             \
        B = *reinterpret_cast<const float4*>(zp_ + 4);                         \
    }
#define ZCVT(rb, A, B)                                                         \
    {                                                                          \
        float vv_[8] = {A.x, A.y, A.z, A.w, B.x, B.y, B.z, B.w};               \
        ushort hb_[8]; float sq_ = 0.f;                                        \
        _Pragma("unroll")                                                      \
        for (int e = 0; e < 8; ++e) {                                          \
            ushort h_ = f2bf(vv_[e] * wz[e]);                                  \
            hb_[e] = h_;                                                       \
            float vr_ = bf2f(h_);                                              \
            sq_ = fmaf(vr_, vr_, sq_);                                         \
        }                                                                      \
        uint4 u_ = make_uint4(                                                 \
            (unsigned)hb_[0] | ((unsigned)hb_[1] << 16),                       \
            (unsigned)hb_[2] | ((unsigned)hb_[3] << 16),                       \
            (unsigned)hb_[4] | ((unsigned)hb_[5] << 16),                       \
            (unsigned)hb_[6] | ((unsigned)hb_[7] << 16));                      \
        int row_ = (rb) * 128 + row_base;                                      \
        int sw_  = row_ * 128 + ((gr * 16) ^ ((row_ & 7) << 4));               \
        *reinterpret_cast<uint4*>(zbw + sw_) = u_;                             \
        sq_ += __shfl_xor(sq_, 1);                                             \
        sq_ += __shfl_xor(sq_, 2);                                             \
        sq_ += __shfl_xor(sq_, 4);                                             \
        if (gr == 0) sm.z2[row_] = sq_ * L2E;                                  \
    }

    {
        float4 dA0, dB0, dA1, dB1, dA2, dB2, dA3, dB3;
        ZLD(0, dA0, dB0)
        ZLD(1, dA1, dB1)
        ZLD(2, dA2, dB2)
        ZLD(3, dA3, dB3)
        ZCVT(0, dA0, dB0)  ZLD(4, dA0, dB0)
        ZCVT(1, dA1, dB1)  ZLD(5, dA1, dB1)
        ZCVT(2, dA2, dB2)  ZLD(6, dA2, dB2)
        ZCVT(3, dA3, dB3)  ZLD(7, dA3, dB3)
        ZCVT(4, dA0, dB0)
        ZCVT(5, dA1, dB1)
        ZCVT(6, dA2, dB2)
        ZCVT(7, dA3, dB3)
    }
#undef ZLD
#undef ZCVT

    sm.al[tid] = alv;

    // ---- convert x (loads long in flight) + xs2 ----
    short8 b0, b1;
    float xs2;
    {
        float wx[16];
#pragma unroll
        for (int h = 0; h < 2; ++h)
#pragma unroll
            for (int e = 0; e < 8; ++e)
                wx[h * 8 + e] = __expf(-0.5f * ls[h * 32 + g * 8 + e]);
        float vv[16] = {xv0.x, xv0.y, xv0.z, xv0.w, xv1.x, xv1.y, xv1.z, xv1.w,
                        xv2.x, xv2.y, xv2.z, xv2.w, xv3.x, xv3.y, xv3.z, xv3.w};
        float sq = 0.f;
        short8 bb[2];
#pragma unroll
        for (int h = 0; h < 2; ++h)
#pragma unroll
            for (int e = 0; e < 8; ++e) {
                ushort hh = f2bf(vv[h * 8 + e] * wx[h * 8 + e]);
                bb[h][e] = (short)hh;
                float xv = bf2f(hh);
                sq = fmaf(xv, xv, sq);
            }
        b0 = bb[0]; b1 = bb[1];
        sq += __shfl_xor(sq, 16);
        sq += __shfl_xor(sq, 32);
        xs2 = sq * L2E;
    }

    __syncthreads();   // z-panel + z2 + al ready (LDS read-only from here)

    // ---- wave-scalar skip bound: zmin = min z2 over all rows ----
    float zmin;
    {
        float mn = sm.z2[lane];
#pragma unroll
        for (int i = 1; i < 16; ++i) mn = fminf(mn, sm.z2[lane + 64 * i]);
        mn = fminf(mn, __shfl_xor(mn, 1));
        mn = fminf(mn, __shfl_xor(mn, 2));
        mn = fminf(mn, __shfl_xor(mn, 4));
        mn = fminf(mn, __shfl_xor(mn, 8));
        mn = fminf(mn, __shfl_xor(mn, 16));
        mn = fminf(mn, __shfl_xor(mn, 32));
        zmin = mn;
    }
    const float thr = SKIP_THR + xs2 + zmin;   // skip iff L2E2*maxdot < thr

    const char* zb = reinterpret_cast<const char*>(sm.zt);
    const int rb0 = p * 128 + ((16 * g)      ^ ((p & 7) << 4));
    const int rb1 = p * 128 + ((64 + 16 * g) ^ ((p & 7) << 4));

    f32x2 accJ = {0.f, 0.f};
    const f32x2 xs2p = {xs2, xs2};

#pragma unroll 4
    for (int it = 0; it < TILES; ++it) {
        short8 a0 = *reinterpret_cast<const short8*>(zb + it * 2048 + rb0);
        short8 a1 = *reinterpret_cast<const short8*>(zb + it * 2048 + rb1);

        f32x4 t = {0.f, 0.f, 0.f, 0.f};
        t = __builtin_amdgcn_mfma_f32_16x16x32_bf16(a0, b0, t, 0, 0, 0);
        t = __builtin_amdgcn_mfma_f32_16x16x32_bf16(a1, b1, t, 0, 0, 0);

        float maxdot = fmaxf(fmaxf(t[0], t[1]), fmaxf(t[2], t[3]));

        if (!__all(maxdot * L2E2 < thr)) {
            // rare path: a real contribution may exist in this tile
            float4 z2 = *reinterpret_cast<const float4*>(&sm.z2[it * 16 + g * 4]);
            float4 a4 = *reinterpret_cast<const float4*>(&sm.al[it * 16 + g * 4]);
            f32x2 z2p0 = {z2.x, z2.y}, z2p1 = {z2.z, z2.w};
            f32x2 d0 = {t[0], t[1]}, d1 = {t[2], t[3]};
            f32x2 arg0 = d0 * L2E2 - (z2p0 + xs2p);
            f32x2 arg1 = d1 * L2E2 - (z2p1 + xs2p);
            f32x2 pv0 = {__builtin_amdgcn_exp2f(arg0.x),
                         __builtin_amdgcn_exp2f(arg0.y)};
            f32x2 pv1 = {__builtin_amdgcn_exp2f(arg1.x),
                         __builtin_amdgcn_exp2f(arg1.y)};
            f32x2 a4p0 = {a4.x, a4.y}, a4p1 = {a4.z, a4.w};
            accJ = accJ + a4p0 * pv0;              // pk_fma
            accJ = accJ + a4p1 * pv1;              // pk_fma
        }
    }

    float r = accJ.x + accJ.y;
    r += __shfl_xor(r, 16);
    r += __shfl_xor(r, 32);
    if (g == 0) out[j] = r;
}

extern "C" void kernel_launch(void* const* d_in, const int* in_sizes, int n_in,
                              void* d_out, int out_size, void* d_ws, size_t ws_size,
                              hipStream_t stream) {
    const float* x     = (const float*)d_in[0];   // (65536, 64)
    const float* z     = (const float*)d_in[1];   // (1024, 64)
    const float* alpha = (const float*)d_in[2];   // (1024,)
    const float* ls    = (const float*)d_in[3];   // (64,)
    float* out = (float*)d_out;                   // (65536, 1)

    igpr_fused<<<dim3(N_X / 256), dim3(1024), 0, stream>>>(x, z, alpha, ls, out);
}

// Round 26
// 20.171 us; speedup vs baseline: 1.1820x; 1.0222x over previous
//
#include <hip/hip_runtime.h>
#include <hip/hip_bf16.h>

#define N_X    65536
#define N_IND  1024
#define N_DESC 64
#define TILES  (N_IND / 16)       // 64 MFMA row-tiles (full z-panel)
#define L2E    1.4426950408889634f
#define L2E2   2.8853900817779268f
#define SKIP_THR (-60.0f)         // 2^-60 * 1024 * |alpha| ~ 4e-15 << tol

typedef __attribute__((ext_vector_type(8))) short  short8;
typedef __attribute__((ext_vector_type(4))) float  f32x4;
typedef __attribute__((ext_vector_type(2))) float  f32x2;

static __device__ __forceinline__ ushort f2bf(float f) {
    union { float f; unsigned u; } a; a.f = f;
    unsigned r = a.u + 0x7FFF + ((a.u >> 16) & 1);   // RNE to bf16
    return (ushort)(r >> 16);
}
static __device__ __forceinline__ float bf2f(ushort h) {
    union { unsigned u; float f; } a; a.u = (unsigned)h << 16;
    return a.f;
}

// ---------------------------------------------------------------------------
// FINAL (= Round 22 champion, reproduced 3x: 20.25/20.23/20.21 us,
// absmax 0.0, full output coverage audited).
// Structure: single fused dispatch, 1024-thr blocks (16 waves, 1 block/CU),
// grid 256. Per block: full weighted z-panel f32->bf16 converted in-register
// and staged once into 128 KB XOR-swizzled LDS (2-deep pipelined granule
// loads; x loads issued first, in flight under staging). Each wave owns 16
// x-columns; loop over 64 tiles: 2 swizzled conflict-free ds_read_b128 +
// 2 chained mfma_16x16x32_bf16 + 4-op skip test vs wave-scalar bound
//   skip iff L2E2*maxdot < SKIP_THR + xs2 + zmin   (zmin = min z2, sound)
// (each skipped term < 2^-60, total < 4e-15 — below f32 accumulation
// granularity; exact epilogue on the kept path if it ever fires).
// Swizzle: byte colb ^= (row&7)<<4 on BOTH write and read (rule #21).
// C/D: col = lane&15 (x-col), row = 4*(lane>>4)+reg (z-row).
// Plateau evidence: R13 rep-profile (loop LDS-issue-bound; staging
// latency-bound), R15/R19/R20 proportional LDS-delta responses;
// R16/R17/R18/R21/R23/R24/R25 restructurings all regressed — VALU/launch/
// register/ws-dirty-read taxes exceed their LDS/latency savings here.
// ---------------------------------------------------------------------------
__global__ __launch_bounds__(1024) void igpr_fused(
        const float* __restrict__ x, const float* __restrict__ z,
        const float* __restrict__ alpha, const float* __restrict__ ls,
        float* __restrict__ out) {
    struct SM {
        uint4 zt[N_IND * 8];   // 1024 rows * 128 B = 128 KB (swizzled)
        float z2[N_IND];       // log2e * ||zw_i||^2
        float al[N_IND];       // alpha
    };
    __shared__ SM sm;          // 136 KB of the CU's 160 KB

    const int tid  = threadIdx.x;
    const int lane = tid & 63;
    const int wave = tid >> 6;
    const int p = lane & 15;          // x-col within strip / D col
    const int g = lane >> 4;          // k-group; D rows 4g..4g+3 (z-rows)
    const int j = blockIdx.x * 256 + wave * 16 + p;   // this lane's x column

    // ---- issue x loads immediately; consumed after z staging ----
    const float* xr = x + (size_t)j * N_DESC;
    float4 xv0 = *reinterpret_cast<const float4*>(xr + g * 8);
    float4 xv1 = *reinterpret_cast<const float4*>(xr + g * 8 + 4);
    float4 xv2 = *reinterpret_cast<const float4*>(xr + 32 + g * 8);
    float4 xv3 = *reinterpret_cast<const float4*>(xr + 32 + g * 8 + 4);
    float  alv = alpha[tid];          // N_IND == blockDim.x

    // ---- per-thread staging weights: cols gr*8 .. gr*8+7 ----
    const int gr = tid & 7;           // granule column-group (fixed per thread)
    const int row_base = tid >> 3;    // row = rb*128 + row_base
    float wz[8];
#pragma unroll
    for (int e = 0; e < 8; ++e) wz[e] = __expf(-0.5f * ls[gr * 8 + e]);

    // ---- z staging: 8 granules, 2-deep pipelined, swizzled dest ----
    char* zbw = reinterpret_cast<char*>(sm.zt);

#define ZLD(rb, A, B)                                                          \
    {                                                                          \
        const float* zp_ = z + (size_t)((rb) * 128 + row_base) * 64 + gr * 8;  \
        A = *reinterpret_cast<const float4*>(zp_);                             \
        B = *reinterpret_cast<const float4*>(zp_ + 4);                         \
    }
#define ZCVT(rb, A, B)                                                         \
    {                                                                          \
        float vv_[8] = {A.x, A.y, A.z, A.w, B.x, B.y, B.z, B.w};               \
        ushort hb_[8]; float sq_ = 0.f;                                        \
        _Pragma("unroll")                                                      \
        for (int e = 0; e < 8; ++e) {                                          \
            ushort h_ = f2bf(vv_[e] * wz[e]);                                  \
            hb_[e] = h_;                                                       \
            float vr_ = bf2f(h_);                                              \
            sq_ = fmaf(vr_, vr_, sq_);                                         \
        }                                                                      \
        uint4 u_ = make_uint4(                                                 \
            (unsigned)hb_[0] | ((unsigned)hb_[1] << 16),                       \
            (unsigned)hb_[2] | ((unsigned)hb_[3] << 16),                       \
            (unsigned)hb_[4] | ((unsigned)hb_[5] << 16),                       \
            (unsigned)hb_[6] | ((unsigned)hb_[7] << 16));                      \
        int row_ = (rb) * 128 + row_base;                                      \
        int sw_  = row_ * 128 + ((gr * 16) ^ ((row_ & 7) << 4));               \
        *reinterpret_cast<uint4*>(zbw + sw_) = u_;                             \
        sq_ += __shfl_xor(sq_, 1);                                             \
        sq_ += __shfl_xor(sq_, 2);                                             \
        sq_ += __shfl_xor(sq_, 4);                                             \
        if (gr == 0) sm.z2[row_] = sq_ * L2E;                                  \
    }

    float4 cA, cB, nA, nB;
    ZLD(0, cA, cB)
    ZLD(1, nA, nB)
    ZCVT(0, cA, cB)  ZLD(2, cA, cB)
    ZCVT(1, nA, nB)  ZLD(3, nA, nB)
    ZCVT(2, cA, cB)  ZLD(4, cA, cB)
    ZCVT(3, nA, nB)  ZLD(5, nA, nB)
    ZCVT(4, cA, cB)  ZLD(6, cA, cB)
    ZCVT(5, nA, nB)  ZLD(7, nA, nB)
    ZCVT(6, cA, cB)
    ZCVT(7, nA, nB)
#undef ZLD
#undef ZCVT

    sm.al[tid] = alv;

    // ---- convert x (loads long in flight) + xs2 ----
    short8 b0, b1;
    float xs2;
    {
        float wx[16];
#pragma unroll
        for (int h = 0; h < 2; ++h)
#pragma unroll
            for (int e = 0; e < 8; ++e)
                wx[h * 8 + e] = __expf(-0.5f * ls[h * 32 + g * 8 + e]);
        float vv[16] = {xv0.x, xv0.y, xv0.z, xv0.w, xv1.x, xv1.y, xv1.z, xv1.w,
                        xv2.x, xv2.y, xv2.z, xv2.w, xv3.x, xv3.y, xv3.z, xv3.w};
        float sq = 0.f;
        short8 bb[2];
#pragma unroll
        for (int h = 0; h < 2; ++h)
#pragma unroll
            for (int e = 0; e < 8; ++e) {
                ushort hh = f2bf(vv[h * 8 + e] * wx[h * 8 + e]);
                bb[h][e] = (short)hh;
                float xv = bf2f(hh);
                sq = fmaf(xv, xv, sq);
            }
        b0 = bb[0]; b1 = bb[1];
        sq += __shfl_xor(sq, 16);
        sq += __shfl_xor(sq, 32);
        xs2 = sq * L2E;
    }

    __syncthreads();   // z-panel + z2 + al ready (LDS read-only from here)

    // ---- wave-scalar skip bound: zmin = min z2 over all rows ----
    float zmin;
    {
        float mn = sm.z2[lane];
#pragma unroll
        for (int i = 1; i < 16; ++i) mn = fminf(mn, sm.z2[lane + 64 * i]);
        mn = fminf(mn, __shfl_xor(mn, 1));
        mn = fminf(mn, __shfl_xor(mn, 2));
        mn = fminf(mn, __shfl_xor(mn, 4));
        mn = fminf(mn, __shfl_xor(mn, 8));
        mn = fminf(mn, __shfl_xor(mn, 16));
        mn = fminf(mn, __shfl_xor(mn, 32));
        zmin = mn;
    }
    const float thr = SKIP_THR + xs2 + zmin;   // skip iff L2E2*maxdot < thr

    const char* zb = reinterpret_cast<const char*>(sm.zt);
    const int rb0 = p * 128 + ((16 * g)      ^ ((p & 7) << 4));
    const int rb1 = p * 128 + ((64 + 16 * g) ^ ((p & 7) << 4));

    f32x2 accJ = {0.f, 0.f};
    const f32x2 xs2p = {xs2, xs2};

#pragma unroll 4
    for (int it = 0; it < TILES; ++it) {
        short8 a0 = *reinterpret_cast<const short8*>(zb + it * 2048 + rb0);
        short8 a1 = *reinterpret_cast<const short8*>(zb + it * 2048 + rb1);

        f32x4 t = {0.f, 0.f, 0.f, 0.f};
        t = __builtin_amdgcn_mfma_f32_16x16x32_bf16(a0, b0, t, 0, 0, 0);
        t = __builtin_amdgcn_mfma_f32_16x16x32_bf16(a1, b1, t, 0, 0, 0);

        float maxdot = fmaxf(fmaxf(t[0], t[1]), fmaxf(t[2], t[3]));

        if (!__all(maxdot * L2E2 < thr)) {
            // rare path: a real contribution may exist in this tile
            float4 z2 = *reinterpret_cast<const float4*>(&sm.z2[it * 16 + g * 4]);
            float4 a4 = *reinterpret_cast<const float4*>(&sm.al[it * 16 + g * 4]);
            f32x2 z2p0 = {z2.x, z2.y}, z2p1 = {z2.z, z2.w};
            f32x2 d0 = {t[0], t[1]}, d1 = {t[2], t[3]};
            f32x2 arg0 = d0 * L2E2 - (z2p0 + xs2p);
            f32x2 arg1 = d1 * L2E2 - (z2p1 + xs2p);
            f32x2 pv0 = {__builtin_amdgcn_exp2f(arg0.x),
                         __builtin_amdgcn_exp2f(arg0.y)};
            f32x2 pv1 = {__builtin_amdgcn_exp2f(arg1.x),
                         __builtin_amdgcn_exp2f(arg1.y)};
            f32x2 a4p0 = {a4.x, a4.y}, a4p1 = {a4.z, a4.w};
            accJ = accJ + a4p0 * pv0;              // pk_fma
            accJ = accJ + a4p1 * pv1;              // pk_fma
        }
    }

    float r = accJ.x + accJ.y;
    r += __shfl_xor(r, 16);
    r += __shfl_xor(r, 32);
    if (g == 0) out[j] = r;
}

extern "C" void kernel_launch(void* const* d_in, const int* in_sizes, int n_in,
                              void* d_out, int out_size, void* d_ws, size_t ws_size,
                              hipStream_t stream) {
    const float* x     = (const float*)d_in[0];   // (65536, 64)
    const float* z     = (const float*)d_in[1];   // (1024, 64)
    const float* alpha = (const float*)d_in[2];   // (1024,)
    const float* ls    = (const float*)d_in[3];   // (64,)
    float* out = (float*)d_out;                   // (65536, 1)

    igpr_fused<<<dim3(N_X / 256), dim3(1024), 0, stream>>>(x, z, alpha, ls, out);
}